// Round 23
// baseline (479.269 us; speedup 1.0000x reference)
//
#include <hip/hip_runtime.h>

#define B_ 32
#define T_ 2048
#define C_ 64
#define NP_ 2060          // unique p positions per batch
#define MSTRIDE 144       // floats per 12x12 matrix in global ws
#define LSTRIDE 148       // padded LDS stride

typedef short short8_t __attribute__((ext_vector_type(8)));   // 8 bf16 (4 VGPR)
typedef float f32x4 __attribute__((ext_vector_type(4)));

__device__ __forceinline__ unsigned short f2bf(float f) {
  unsigned u = __float_as_uint(f);
  return (unsigned short)((u + 0x7FFFu + ((u >> 16) & 1u)) >> 16);
}
__device__ __forceinline__ float bf2f(unsigned short s) {
  return __uint_as_float(((unsigned)s) << 16);
}

// ------------------------------------------------------------------
// K1 (MFMA): M[b][p][e] = sum_c dx[p][c] * ask[c][e], scaled 2^-4.
// (validated rounds 10/13/14 — unchanged)
// ------------------------------------------------------------------
__global__ __launch_bounds__(256) void k1_mfma(const float* __restrict__ x,
                                               const float* __restrict__ A,
                                               float* __restrict__ M) {
  __shared__ unsigned int askw[9216];   // 36 KB
  const int b = blockIdx.y;
  const int p0 = blockIdx.x * 64;
  const int tid = threadIdx.x;
  const float sc = 1.0f / 16.0f;        // 2^-4

  for (int P = tid; P < 4608; P += 256) {
    const int j2 = P & 3;
    const int col = (P >> 2) & 15;
    const int koct = (P >> 6) & 3;
    const int rest = P >> 8;            // 0..17
    const int tile = rest % 9;
    const int ks = rest / 9;
    const int e = tile * 16 + col;      // < 144
    const int h = e / 12, w = e - h * 12;
    const int c0 = ks * 32 + koct * 8 + j2 * 2;
    const float v0 = (A[c0 * 144 + e] - A[c0 * 144 + w * 12 + h]) * sc;
    const float v1 = (A[(c0 + 1) * 144 + e] - A[(c0 + 1) * 144 + w * 12 + h]) * sc;
    const unsigned short h0 = f2bf(v0), h1 = f2bf(v1);
    const unsigned short l0 = f2bf(v0 - bf2f(h0)), l1 = f2bf(v1 - bf2f(h1));
    const int widx = (((ks * 9 + tile) * 4 + koct) * 16 + col) * 4 + j2;
    askw[widx] = ((unsigned)h1 << 16) | h0;
    askw[4608 + widx] = ((unsigned)l1 << 16) | l0;
  }
  __syncthreads();

  const int wv = tid >> 6;
  const int lane = tid & 63;
  const int mrow = lane & 15;
  const int koct = lane >> 4;
  const int p = p0 + wv * 16 + mrow;
  const int i1 = min(max(p - 7, 0), T_ - 1);
  const int i2 = min(max(p - 5, 0), T_ - 1);
  const float* xb = x + (size_t)b * T_ * C_;

  short8_t ah[2], al[2];
#pragma unroll
  for (int ks = 0; ks < 2; ++ks) {
    const int c0 = ks * 32 + koct * 8;
    const float4 u1a = *(const float4*)(xb + (size_t)i1 * C_ + c0);
    const float4 u1b = *(const float4*)(xb + (size_t)i1 * C_ + c0 + 4);
    const float4 u2a = *(const float4*)(xb + (size_t)i2 * C_ + c0);
    const float4 u2b = *(const float4*)(xb + (size_t)i2 * C_ + c0 + 4);
    float d[8];
    d[0] = u2a.x - u1a.x; d[1] = u2a.y - u1a.y;
    d[2] = u2a.z - u1a.z; d[3] = u2a.w - u1a.w;
    d[4] = u2b.x - u1b.x; d[5] = u2b.y - u1b.y;
    d[6] = u2b.z - u1b.z; d[7] = u2b.w - u1b.w;
#pragma unroll
    for (int j = 0; j < 8; ++j) {
      const unsigned short hs = f2bf(d[j]);
      ah[ks][j] = (short)hs;
      al[ks][j] = (short)f2bf(d[j] - bf2f(hs));
    }
  }

  float* Mb = M + (size_t)b * NP_ * MSTRIDE;
  const int dcol = lane & 15;
  const int pbase = p0 + wv * 16 + (lane >> 4) * 4;
  const char* lds = (const char*)askw;
#pragma unroll
  for (int tile = 0; tile < 9; ++tile) {
    f32x4 acc = {0.f, 0.f, 0.f, 0.f};
#pragma unroll
    for (int ks = 0; ks < 2; ++ks) {
      const int fb = (((ks * 9 + tile) * 4 + koct) * 16 + dcol) * 16;  // byte
      const short8_t bh = *(const short8_t*)(lds + fb);
      const short8_t bl = *(const short8_t*)(lds + 18432 + fb);
      acc = __builtin_amdgcn_mfma_f32_16x16x32_bf16(ah[ks], bh, acc, 0, 0, 0);
      acc = __builtin_amdgcn_mfma_f32_16x16x32_bf16(ah[ks], bl, acc, 0, 0, 0);
      acc = __builtin_amdgcn_mfma_f32_16x16x32_bf16(al[ks], bh, acc, 0, 0, 0);
    }
#pragma unroll
    for (int reg = 0; reg < 4; ++reg) {
      const int pr = pbase + reg;
      if (pr < NP_) Mb[(size_t)pr * MSTRIDE + tile * 16 + dcol] = acc[reg];
    }
  }
}

// ------------------------------------------------------------------
// Quad matmul via fused DPP-FMA (round-17/20 form — phase A only).
// ------------------------------------------------------------------
#define QFMAC(C, Bv, Av, O)                                              \
  asm("v_fmac_f32_dpp %0, %1, %2 quad_perm:[" #O "," #O "," #O "," #O    \
      "] row_mask:0xf bank_mask:0xf"                                     \
      : "+v"(C) : "v"(Bv), "v"(Av))
#define QMUL(C, Bv, Av, O)                                               \
  asm("v_mul_f32_dpp %0, %1, %2 quad_perm:[" #O "," #O "," #O "," #O     \
      "] row_mask:0xf bank_mask:0xf"                                     \
      : "=v"(C) : "v"(Bv), "v"(Av))

template <bool ACC>
__device__ __forceinline__ void qmm_t(const float a[3][12], const float b[3][12],
                                      float c[3][12]) {
#define QMM_K(OWNER, E, FIRST)                                           \
  {                                                                      \
    _Pragma("unroll")                                                    \
    for (int i = 0; i < 3; ++i) {                                        \
      const float av = a[i][3 * OWNER + E];                              \
      _Pragma("unroll")                                                  \
      for (int j = 0; j < 12; ++j) {                                     \
        if (FIRST && !ACC) { QMUL(c[i][j], b[E][j], av, OWNER); }        \
        else              { QFMAC(c[i][j], b[E][j], av, OWNER); }        \
      }                                                                  \
    }                                                                    \
  }
  QMM_K(0, 0, true)  QMM_K(0, 1, false) QMM_K(0, 2, false)
  QMM_K(1, 0, false) QMM_K(1, 1, false) QMM_K(1, 2, false)
  QMM_K(2, 0, false) QMM_K(2, 1, false) QMM_K(2, 2, false)
  QMM_K(3, 0, false) QMM_K(3, 1, false) QMM_K(3, 2, false)
#undef QMM_K
}
__device__ __forceinline__ void qmm(const float a[3][12], const float b[3][12],
                                    float c[3][12]) { qmm_t<false>(a, b, c); }
__device__ __forceinline__ void qmma(const float a[3][12], const float b[3][12],
                                     float c[3][12]) { qmm_t<true>(a, b, c); }

// ------------------------------------------------------------------
// Plain-FMA matmul, B broadcast-read from LDS (quad-uniform addrs).
// 36 ds_read_b128 (2-way banks), 432 plain FMA.
// ------------------------------------------------------------------
__device__ __forceinline__ void matmul_rows(const float a[3][12],
                                            const float* lb, float c[3][12]) {
#pragma unroll
  for (int i = 0; i < 3; ++i)
#pragma unroll
    for (int j = 0; j < 12; ++j) c[i][j] = 0.f;
#pragma unroll
  for (int k = 0; k < 12; ++k) {
    float4 b0 = *(const float4*)(lb + k * 12 + 0);
    float4 b1 = *(const float4*)(lb + k * 12 + 4);
    float4 b2 = *(const float4*)(lb + k * 12 + 8);
#pragma unroll
    for (int i = 0; i < 3; ++i) {
      const float a_ = a[i][k];
      c[i][0] += a_ * b0.x;  c[i][1] += a_ * b0.y;  c[i][2]  += a_ * b0.z;  c[i][3]  += a_ * b0.w;
      c[i][4] += a_ * b1.x;  c[i][5] += a_ * b1.y;  c[i][6]  += a_ * b1.z;  c[i][7]  += a_ * b1.w;
      c[i][8] += a_ * b2.x;  c[i][9] += a_ * b2.y;  c[i][10] += a_ * b2.z;  c[i][11] += a_ * b2.w;
    }
  }
}

// ------------------------------------------------------------------
// K23 (fused expm + chain): 320 threads = 80 quads per block of 64 windows.
// Phase A: quads 0..75 expm M[t0+q] (DPP qmm, PS-6 + 4 squarings) -> eb[q].
// Phase B (UNPAIRED, r23): quads 0..63 each own window t = t0+q:
//   Z = E(t)*E(t+2)*...*E(t+12) via 6 LDS-broadcast matmuls. 4/5 waves
//   active (vs 2/5 paired) — targets the latency-bound 44% VALUBusy.
// ------------------------------------------------------------------
__global__ __launch_bounds__(320) void k23_fused(const float* __restrict__ M,
                                                 const float* __restrict__ x,
                                                 float* __restrict__ out) {
  __shared__ float eb[76][LSTRIDE];     // 44992 B -> 3 blocks/CU
  const int b = blockIdx.y;
  const int t0 = blockIdx.x * 64;
  const int tid = threadIdx.x;
  const int q = tid >> 2;               // quad 0..79
  const int r = tid & 3;                // rows 3r..3r+2

  if (q < 76) {
    const int p = t0 + q;               // <= 2059 always
    const float* gp = M + ((size_t)b * NP_ + p) * MSTRIDE + 36 * r;
    float a[3][12], t2[3][12], t3[3][12];
#pragma unroll
    for (int i = 0; i < 3; ++i)
#pragma unroll
      for (int q4 = 0; q4 < 3; ++q4) {
        float4 v = *(const float4*)(gp + i * 12 + q4 * 4);
        a[i][q4 * 4 + 0] = v.x;
        a[i][q4 * 4 + 1] = v.y;
        a[i][q4 * 4 + 2] = v.z;
        a[i][q4 * 4 + 3] = v.w;
      }

    qmm(a, a, t2);      // M2
    qmm(t2, a, t3);     // M3
#pragma unroll
    for (int i = 0; i < 3; ++i)
#pragma unroll
      for (int j = 0; j < 12; ++j) {
        const float av = a[i][j], t2v = t2[i][j], t3v = t3[i][j];
        t2[i][j] = av + t2v * 0.5f + t3v * (1.0f / 6.0f) +
                   ((j == 3 * r + i) ? 1.0f : 0.0f);
        a[i][j] = av * (1.0f / 24.0f) + t2v * (1.0f / 120.0f) +
                  t3v * (1.0f / 720.0f);
      }
    qmma(t3, a, t2);    // t2 += M3*W  (degree-6 poly)

    // 4 squarings; E lands in t2
    qmm(t2, t2, t3);
    qmm(t3, t3, t2);
    qmm(t2, t2, t3);
    qmm(t3, t3, t2);

    // E -> LDS
    float* lb = &eb[q][0];
#pragma unroll
    for (int i = 0; i < 3; ++i) {
      const int row = 3 * r + i;
      *(float4*)(lb + row * 12 + 0) = make_float4(t2[i][0], t2[i][1], t2[i][2],  t2[i][3]);
      *(float4*)(lb + row * 12 + 4) = make_float4(t2[i][4], t2[i][5], t2[i][6],  t2[i][7]);
      *(float4*)(lb + row * 12 + 8) = make_float4(t2[i][8], t2[i][9], t2[i][10], t2[i][11]);
    }
  }
  __syncthreads();

  if (q >= 64) return;                  // wave 4 done
  const int t1 = t0 + q;                // one window per quad

  float z[3][12], c[3][12];
#pragma unroll
  for (int i = 0; i < 3; ++i) {
    const float* zp = &eb[q][(3 * r + i) * 12];
    float4 v0 = *(const float4*)(zp + 0);
    float4 v1 = *(const float4*)(zp + 4);
    float4 v2 = *(const float4*)(zp + 8);
    z[i][0] = v0.x; z[i][1] = v0.y; z[i][2]  = v0.z; z[i][3]  = v0.w;
    z[i][4] = v1.x; z[i][5] = v1.y; z[i][6]  = v1.z; z[i][7]  = v1.w;
    z[i][8] = v2.x; z[i][9] = v2.y; z[i][10] = v2.z; z[i][11] = v2.w;
  }
  matmul_rows(z, &eb[q + 2][0], c);
  matmul_rows(c, &eb[q + 4][0], z);
  matmul_rows(z, &eb[q + 6][0], c);
  matmul_rows(c, &eb[q + 8][0], z);
  matmul_rows(z, &eb[q + 10][0], c);
  matmul_rows(c, &eb[q + 12][0], z);    // z = E(t)...E(t+12)

  const size_t obase = ((size_t)b * T_ + t1) * 208;
#pragma unroll
  for (int i = 0; i < 3; ++i) {
    const int row = 3 * r + i;
    *(float4*)(out + obase + row * 12 + 0) = make_float4(z[i][0], z[i][1], z[i][2],  z[i][3]);
    *(float4*)(out + obase + row * 12 + 4) = make_float4(z[i][4], z[i][5], z[i][6],  z[i][7]);
    *(float4*)(out + obase + row * 12 + 8) = make_float4(z[i][8], z[i][9], z[i][10], z[i][11]);
  }
  const int xi = min(max(t1 - 7, 0), T_ - 1);
  const float* xr = x + ((size_t)b * T_ + xi) * C_ + 16 * r;
#pragma unroll
  for (int qd = 0; qd < 4; ++qd) {
    *(float4*)(out + obase + 144 + 16 * r + qd * 4) = *(const float4*)(xr + qd * 4);
  }
}

// ------------------------------------------------------------------
extern "C" void kernel_launch(void* const* d_in, const int* in_sizes, int n_in,
                              void* d_out, int out_size, void* d_ws, size_t ws_size,
                              hipStream_t stream) {
  (void)in_sizes; (void)n_in; (void)out_size;
  const float* x = (const float*)d_in[0];
  const float* A = (const float*)d_in[1];
  float* out = (float*)d_out;
  float* M = (float*)d_ws;

  const size_t need = (size_t)B_ * NP_ * MSTRIDE * sizeof(float);  // ~38 MB
  if (ws_size < need) return;

  k1_mfma<<<dim3(33, B_), 256, 0, stream>>>(x, A, M);
  k23_fused<<<dim3(T_ / 64, B_), 320, 0, stream>>>(M, x, out);   // 32 x 32
}

// Round 24
// 101.896 us; speedup vs baseline: 4.7035x; 4.7035x over previous
//
#include <hip/hip_runtime.h>

#define B_ 32
#define T_ 2048
#define C_ 64
#define NP_ 2060          // unique p positions per batch
#define MSTRIDE 144       // floats per 12x12 matrix in global ws
#define LSTRIDE 148       // padded LDS stride

typedef short short8_t __attribute__((ext_vector_type(8)));   // 8 bf16 (4 VGPR)
typedef float f32x4 __attribute__((ext_vector_type(4)));

__device__ __forceinline__ unsigned short f2bf(float f) {
  unsigned u = __float_as_uint(f);
  return (unsigned short)((u + 0x7FFFu + ((u >> 16) & 1u)) >> 16);
}
__device__ __forceinline__ float bf2f(unsigned short s) {
  return __uint_as_float(((unsigned)s) << 16);
}

// ------------------------------------------------------------------
// K1 (MFMA): M[b][p][e] = sum_c dx[p][c] * ask[c][e], scaled 2^-4.
// (validated rounds 10/13/14)
// ------------------------------------------------------------------
__global__ __launch_bounds__(256) void k1_mfma(const float* __restrict__ x,
                                               const float* __restrict__ A,
                                               float* __restrict__ M) {
  __shared__ unsigned int askw[9216];   // 36 KB
  const int b = blockIdx.y;
  const int p0 = blockIdx.x * 64;
  const int tid = threadIdx.x;
  const float sc = 1.0f / 16.0f;        // 2^-4

  for (int P = tid; P < 4608; P += 256) {
    const int j2 = P & 3;
    const int col = (P >> 2) & 15;
    const int koct = (P >> 6) & 3;
    const int rest = P >> 8;            // 0..17
    const int tile = rest % 9;
    const int ks = rest / 9;
    const int e = tile * 16 + col;      // < 144
    const int h = e / 12, w = e - h * 12;
    const int c0 = ks * 32 + koct * 8 + j2 * 2;
    const float v0 = (A[c0 * 144 + e] - A[c0 * 144 + w * 12 + h]) * sc;
    const float v1 = (A[(c0 + 1) * 144 + e] - A[(c0 + 1) * 144 + w * 12 + h]) * sc;
    const unsigned short h0 = f2bf(v0), h1 = f2bf(v1);
    const unsigned short l0 = f2bf(v0 - bf2f(h0)), l1 = f2bf(v1 - bf2f(h1));
    const int widx = (((ks * 9 + tile) * 4 + koct) * 16 + col) * 4 + j2;
    askw[widx] = ((unsigned)h1 << 16) | h0;
    askw[4608 + widx] = ((unsigned)l1 << 16) | l0;
  }
  __syncthreads();

  const int wv = tid >> 6;
  const int lane = tid & 63;
  const int mrow = lane & 15;
  const int koct = lane >> 4;
  const int p = p0 + wv * 16 + mrow;
  const int i1 = min(max(p - 7, 0), T_ - 1);
  const int i2 = min(max(p - 5, 0), T_ - 1);
  const float* xb = x + (size_t)b * T_ * C_;

  short8_t ah[2], al[2];
#pragma unroll
  for (int ks = 0; ks < 2; ++ks) {
    const int c0 = ks * 32 + koct * 8;
    const float4 u1a = *(const float4*)(xb + (size_t)i1 * C_ + c0);
    const float4 u1b = *(const float4*)(xb + (size_t)i1 * C_ + c0 + 4);
    const float4 u2a = *(const float4*)(xb + (size_t)i2 * C_ + c0);
    const float4 u2b = *(const float4*)(xb + (size_t)i2 * C_ + c0 + 4);
    float d[8];
    d[0] = u2a.x - u1a.x; d[1] = u2a.y - u1a.y;
    d[2] = u2a.z - u1a.z; d[3] = u2a.w - u1a.w;
    d[4] = u2b.x - u1b.x; d[5] = u2b.y - u1b.y;
    d[6] = u2b.z - u1b.z; d[7] = u2b.w - u1b.w;
#pragma unroll
    for (int j = 0; j < 8; ++j) {
      const unsigned short hs = f2bf(d[j]);
      ah[ks][j] = (short)hs;
      al[ks][j] = (short)f2bf(d[j] - bf2f(hs));
    }
  }

  float* Mb = M + (size_t)b * NP_ * MSTRIDE;
  const int dcol = lane & 15;
  const int pbase = p0 + wv * 16 + (lane >> 4) * 4;
  const char* lds = (const char*)askw;
#pragma unroll
  for (int tile = 0; tile < 9; ++tile) {
    f32x4 acc = {0.f, 0.f, 0.f, 0.f};
#pragma unroll
    for (int ks = 0; ks < 2; ++ks) {
      const int fb = (((ks * 9 + tile) * 4 + koct) * 16 + dcol) * 16;  // byte
      const short8_t bh = *(const short8_t*)(lds + fb);
      const short8_t bl = *(const short8_t*)(lds + 18432 + fb);
      acc = __builtin_amdgcn_mfma_f32_16x16x32_bf16(ah[ks], bh, acc, 0, 0, 0);
      acc = __builtin_amdgcn_mfma_f32_16x16x32_bf16(ah[ks], bl, acc, 0, 0, 0);
      acc = __builtin_amdgcn_mfma_f32_16x16x32_bf16(al[ks], bh, acc, 0, 0, 0);
    }
#pragma unroll
    for (int reg = 0; reg < 4; ++reg) {
      const int pr = pbase + reg;
      if (pr < NP_) Mb[(size_t)pr * MSTRIDE + tile * 16 + dcol] = acc[reg];
    }
  }
}

// ------------------------------------------------------------------
// Quad matmul via fused DPP-FMA (round-14/17 form — VGPR 64, high
// occupancy; empirically best across rounds 17-23).
// ------------------------------------------------------------------
#define QFMAC(C, Bv, Av, O)                                              \
  asm("v_fmac_f32_dpp %0, %1, %2 quad_perm:[" #O "," #O "," #O "," #O    \
      "] row_mask:0xf bank_mask:0xf"                                     \
      : "+v"(C) : "v"(Bv), "v"(Av))
#define QMUL(C, Bv, Av, O)                                               \
  asm("v_mul_f32_dpp %0, %1, %2 quad_perm:[" #O "," #O "," #O "," #O     \
      "] row_mask:0xf bank_mask:0xf"                                     \
      : "=v"(C) : "v"(Bv), "v"(Av))

template <bool ACC>
__device__ __forceinline__ void qmm_t(const float a[3][12], const float b[3][12],
                                      float c[3][12]) {
#define QMM_K(OWNER, E, FIRST)                                           \
  {                                                                      \
    _Pragma("unroll")                                                    \
    for (int i = 0; i < 3; ++i) {                                        \
      const float av = a[i][3 * OWNER + E];                              \
      _Pragma("unroll")                                                  \
      for (int j = 0; j < 12; ++j) {                                     \
        if (FIRST && !ACC) { QMUL(c[i][j], b[E][j], av, OWNER); }        \
        else              { QFMAC(c[i][j], b[E][j], av, OWNER); }        \
      }                                                                  \
    }                                                                    \
  }
  QMM_K(0, 0, true)  QMM_K(0, 1, false) QMM_K(0, 2, false)
  QMM_K(1, 0, false) QMM_K(1, 1, false) QMM_K(1, 2, false)
  QMM_K(2, 0, false) QMM_K(2, 1, false) QMM_K(2, 2, false)
  QMM_K(3, 0, false) QMM_K(3, 1, false) QMM_K(3, 2, false)
#undef QMM_K
}
__device__ __forceinline__ void qmm(const float a[3][12], const float b[3][12],
                                    float c[3][12]) { qmm_t<false>(a, b, c); }
__device__ __forceinline__ void qmma(const float a[3][12], const float b[3][12],
                                     float c[3][12]) { qmm_t<true>(a, b, c); }

// ------------------------------------------------------------------
// K23 (fused expm + chain): 320 threads = 80 quads per block of 64 windows.
// Phase A: quads 0..75 expm M[t0+q] (PS-6 + 4 squarings) -> eb[q] in LDS.
//   p = t0+q <= 1984+75 = 2059 = NP_-1: never OOB, no clamps.
// Phase B (after one barrier): quads 0..31 compute window pairs (t,t+2):
//   R = E(t+2)..E(t+12) (5 qmm), Z(t)=E(t)*R, Z(t+2)=R*E(t+14).
// E never touches global memory.
// ------------------------------------------------------------------
__global__ __launch_bounds__(320) void k23_fused(const float* __restrict__ M,
                                                 const float* __restrict__ x,
                                                 float* __restrict__ out) {
  __shared__ float eb[76][LSTRIDE];     // 44992 B -> 3 blocks/CU
  const int b = blockIdx.y;
  const int t0 = blockIdx.x * 64;
  const int tid = threadIdx.x;
  const int q = tid >> 2;               // quad 0..79
  const int r = tid & 3;                // rows 3r..3r+2

  if (q < 76) {
    const int p = t0 + q;               // <= 2059 always
    const float* gp = M + ((size_t)b * NP_ + p) * MSTRIDE + 36 * r;
    float a[3][12], t2[3][12], t3[3][12];
#pragma unroll
    for (int i = 0; i < 3; ++i)
#pragma unroll
      for (int q4 = 0; q4 < 3; ++q4) {
        float4 v = *(const float4*)(gp + i * 12 + q4 * 4);
        a[i][q4 * 4 + 0] = v.x;
        a[i][q4 * 4 + 1] = v.y;
        a[i][q4 * 4 + 2] = v.z;
        a[i][q4 * 4 + 3] = v.w;
      }

    qmm(a, a, t2);      // M2
    qmm(t2, a, t3);     // M3
#pragma unroll
    for (int i = 0; i < 3; ++i)
#pragma unroll
      for (int j = 0; j < 12; ++j) {
        const float av = a[i][j], t2v = t2[i][j], t3v = t3[i][j];
        t2[i][j] = av + t2v * 0.5f + t3v * (1.0f / 6.0f) +
                   ((j == 3 * r + i) ? 1.0f : 0.0f);
        a[i][j] = av * (1.0f / 24.0f) + t2v * (1.0f / 120.0f) +
                  t3v * (1.0f / 720.0f);
      }
    qmma(t3, a, t2);    // t2 += M3*W  (degree-6 poly)

    // 4 squarings; E lands in t2
    qmm(t2, t2, t3);
    qmm(t3, t3, t2);
    qmm(t2, t2, t3);
    qmm(t3, t3, t2);

    // E -> LDS
    float* lb = &eb[q][0];
#pragma unroll
    for (int i = 0; i < 3; ++i) {
      const int row = 3 * r + i;
      *(float4*)(lb + row * 12 + 0) = make_float4(t2[i][0], t2[i][1], t2[i][2],  t2[i][3]);
      *(float4*)(lb + row * 12 + 4) = make_float4(t2[i][4], t2[i][5], t2[i][6],  t2[i][7]);
      *(float4*)(lb + row * 12 + 8) = make_float4(t2[i][8], t2[i][9], t2[i][10], t2[i][11]);
    }
  }
  __syncthreads();

  if (q >= 32) return;                  // waves 2-4 done
  const int par = q & 1, jj = q >> 1;   // jj 0..15
  const int tloc = 4 * jj + par;        // 0..61; +2 covers all 64 windows
  const int t1 = t0 + tloc;

#define LOADB(DST, IDX)                                                  \
  {                                                                      \
    const float* ep = &eb[(IDX)][(3 * r) * 12];                          \
    _Pragma("unroll")                                                    \
    for (int i = 0; i < 3; ++i) {                                        \
      float4 v0 = *(const float4*)(ep + i * 12 + 0);                     \
      float4 v1 = *(const float4*)(ep + i * 12 + 4);                     \
      float4 v2 = *(const float4*)(ep + i * 12 + 8);                     \
      DST[i][0] = v0.x; DST[i][1] = v0.y; DST[i][2]  = v0.z; DST[i][3]  = v0.w; \
      DST[i][4] = v1.x; DST[i][5] = v1.y; DST[i][6]  = v1.z; DST[i][7]  = v1.w; \
      DST[i][8] = v2.x; DST[i][9] = v2.y; DST[i][10] = v2.z; DST[i][11] = v2.w; \
    }                                                                    \
  }

#define STOREZ(SRCZ, TW)                                                 \
  {                                                                      \
    const size_t obase = ((size_t)b * T_ + (TW)) * 208;                  \
    _Pragma("unroll")                                                    \
    for (int i = 0; i < 3; ++i) {                                        \
      const int row = 3 * r + i;                                         \
      *(float4*)(out + obase + row * 12 + 0) =                           \
          make_float4(SRCZ[i][0], SRCZ[i][1], SRCZ[i][2],  SRCZ[i][3]);  \
      *(float4*)(out + obase + row * 12 + 4) =                           \
          make_float4(SRCZ[i][4], SRCZ[i][5], SRCZ[i][6],  SRCZ[i][7]);  \
      *(float4*)(out + obase + row * 12 + 8) =                           \
          make_float4(SRCZ[i][8], SRCZ[i][9], SRCZ[i][10], SRCZ[i][11]); \
    }                                                                    \
    const int xi = min(max((TW) - 7, 0), T_ - 1);                        \
    const float* xr = x + ((size_t)b * T_ + xi) * C_ + 16 * r;           \
    _Pragma("unroll")                                                    \
    for (int qd = 0; qd < 4; ++qd) {                                     \
      *(float4*)(out + obase + 144 + 16 * r + qd * 4) =                  \
          *(const float4*)(xr + qd * 4);                                 \
    }                                                                    \
  }

  float rr[3][12], cc[3][12], bb[3][12];
  LOADB(rr, tloc + 2);                    // R = E(t+2)
  LOADB(bb, tloc + 4);  qmm(rr, bb, cc);
  LOADB(bb, tloc + 6);  qmm(cc, bb, rr);
  LOADB(bb, tloc + 8);  qmm(rr, bb, cc);
  LOADB(bb, tloc + 10); qmm(cc, bb, rr);
  LOADB(bb, tloc + 12); qmm(rr, bb, cc);  // cc = R = E(t+2)...E(t+12)

  LOADB(bb, tloc);      qmm(bb, cc, rr);  // Z(t) = E(t)*R
  STOREZ(rr, t1);
  LOADB(bb, tloc + 14); qmm(cc, bb, rr);  // Z(t+2) = R*E(t+14)
  STOREZ(rr, t1 + 2);
#undef LOADB
#undef STOREZ
}

// ------------------------------------------------------------------
extern "C" void kernel_launch(void* const* d_in, const int* in_sizes, int n_in,
                              void* d_out, int out_size, void* d_ws, size_t ws_size,
                              hipStream_t stream) {
  (void)in_sizes; (void)n_in; (void)out_size;
  const float* x = (const float*)d_in[0];
  const float* A = (const float*)d_in[1];
  float* out = (float*)d_out;
  float* M = (float*)d_ws;

  const size_t need = (size_t)B_ * NP_ * MSTRIDE * sizeof(float);  // ~38 MB
  if (ws_size < need) return;

  k1_mfma<<<dim3(33, B_), 256, 0, stream>>>(x, A, M);
  k23_fused<<<dim3(T_ / 64, B_), 320, 0, stream>>>(M, x, out);   // 32 x 32
}